// Round 13
// baseline (506.708 us; speedup 1.0000x reference)
//
#include <hip/hip_runtime.h>

// ============================================================================
// ActorModel fused inference, MI355X (gfx950)
//
// Math restructuring (exact w.r.t. the reference up to fp rounding):
//   h0 == 0, c0 == 0 (fixed zero inputs)  =>  Whh term and f-gate vanish.
//   gates = [wave|wait|neigh][B,72] @ Wf.T + bias_f     (branch Linears folded)
//   i,o rows pre-scaled by -log2e ; g rows by +2*log2e  (activations -> exp2)
//   c = sig(i)*tanh(g) = (Eg-1) / ((1+Ei)(1+Eg)),  Ei=2^i', Eg=2^g'
//   h = sig(o)*tanh(c) = (Ec-1) / ((1+Eo)(1+Ec)),  Ec=2^(2c*log2e)
//   out = softmax(h @ Wout.T + bout)
//
// R13 (merged experiment; R11 unroll never ran, infra): R9 counters showed
// occupancy 38% because grid 1024/256CU = 4 blocks/CU x 4 waves = 16 waves/CU
// (grid-imposed; VGPR 28 and LDS 27KB left headroom unused). At 3-4 waves/
// SIMD the ~150-300cy per-ntile L2 stall is unhidden. This round: (1) grid
// 2048 x 32 batches, LDS 13.4KB -> 8 blocks/CU -> 32 waves/CU cap, with
// __launch_bounds__(256,8) capping VGPR at 64; (2) compile-time template<CNT>
// ntile loop (full unroll -> compiler pipelines tile j+1 loads over tile j
// compute). Counters disentangle: OccupancyPercent shows lever (1) engaged;
// dur/VGPR_Count show (2)/spills. Cost accepted: Wf L2 traffic doubles to
// ~734MB ~= 21us at L2 BW (overlappable) - the new floor term.
// Predict: occ 38->70-95, fused_main 60->25-35us, total 327->292-302.
//
// Precision: fp16 operands; measured absmax 9.8e-4 (passed). f16 MFMA == bf16.
// ============================================================================

#define LOG2E 1.4426950408889634f

typedef _Float16 half8v __attribute__((ext_vector_type(8)));
typedef _Float16 half4v __attribute__((ext_vector_type(4)));
typedef float float4v __attribute__((ext_vector_type(4)));

#if defined(__has_builtin)
#  if __has_builtin(__builtin_amdgcn_mfma_f32_16x16x16f16)
#    define MFMA16(a, b, c) __builtin_amdgcn_mfma_f32_16x16x16f16(a, b, c, 0, 0, 0)
#  elif __has_builtin(__builtin_amdgcn_mfma_f32_16x16x16_f16)
#    define MFMA16(a, b, c) __builtin_amdgcn_mfma_f32_16x16x16_f16(a, b, c, 0, 0, 0)
#  else
#    define MFMA16(a, b, c) __builtin_amdgcn_mfma_f32_16x16x16f16(a, b, c, 0, 0, 0)
#  endif
#  if __has_builtin(__builtin_amdgcn_exp2f)
#    define EXP2(x) __builtin_amdgcn_exp2f(x)
#  else
#    define EXP2(x) __builtin_exp2f(x)
#  endif
#  if __has_builtin(__builtin_amdgcn_rcpf)
#    define RCP(x) __builtin_amdgcn_rcpf(x)
#  else
#    define RCP(x) (1.0f / (x))
#  endif
#else
#  define MFMA16(a, b, c) __builtin_amdgcn_mfma_f32_16x16x16f16(a, b, c, 0, 0, 0)
#  define EXP2(x) __builtin_exp2f(x)
#  define RCP(x) (1.0f / (x))
#endif

__device__ __forceinline__ unsigned short f2h(float x) {
  return __builtin_bit_cast(unsigned short, (_Float16)x);
}

// ---------------------------------------------------------------------------
// Wf layout: [35 ntile][10240 B tile]; tile = [3 gate][16 unit][104 f16 (k,
// 96 used + 8 pad)] + 256 B tail pad  => 640 uint4 / tile.
// Blocks 0..629: Wf fold. Blocks 630..636: biasF. Block 637: WoutF frags.
// ---------------------------------------------------------------------------
__global__ void prep_wb(const float* __restrict__ Wih, const float* __restrict__ W1,
                        const float* __restrict__ W2, const float* __restrict__ W3,
                        const float* __restrict__ b1, const float* __restrict__ b2,
                        const float* __restrict__ b3, const float* __restrict__ bih,
                        const float* __restrict__ bhh, const float* __restrict__ Wout,
                        unsigned short* __restrict__ Wf, float* __restrict__ biasF,
                        uint2* __restrict__ WoutF) {
  if (blockIdx.x < 630) {
    int idx = blockIdx.x * 256 + threadIdx.x;        // 3*560*96 = 161280 exact
    int k = idx % 96;
    int u = (idx / 96) % 560;
    int t = idx / (96 * 560);                        // 0:i 1:g 2:o
    float val = 0.f;
    if (u < 548 && k < 72) {
      int row = u + (t == 0 ? 0 : (t == 1 ? 1096 : 1644));
      const float* wr = Wih + (size_t)row * 224;
      float s = 0.f;
      if (k < 12) {
        #pragma unroll 16
        for (int m = 0; m < 128; ++m) s += wr[m] * W1[m * 12 + k];
      } else if (k < 24) {
        int kk = k - 12;
        #pragma unroll 16
        for (int m = 0; m < 32; ++m) s += wr[128 + m] * W2[m * 12 + kk];
      } else {
        int kk = k - 24;
        #pragma unroll 16
        for (int m = 0; m < 64; ++m) s += wr[160 + m] * W3[m * 48 + kk];
      }
      val = s * (t == 1 ? 2.f * LOG2E : -LOG2E);
    }
    size_t off = (size_t)(u >> 4) * 5120 + (size_t)t * 1664 + (size_t)(u & 15) * 104 + k;
    Wf[off] = f2h(val);
  } else if (blockIdx.x < 637) {
    int idx = (blockIdx.x - 630) * 256 + threadIdx.x;
    if (idx >= 1680) return;
    int u = idx % 560, t = idx / 560;
    float val = 0.f;
    if (u < 548) {
      int row = u + (t == 0 ? 0 : (t == 1 ? 1096 : 1644));
      const float* wr = Wih + (size_t)row * 224;
      float s = bih[row] + bhh[row];
      #pragma unroll 16
      for (int m = 0; m < 128; ++m) s += wr[m] * b1[m];
      #pragma unroll 16
      for (int m = 0; m < 32; ++m) s += wr[128 + m] * b2[m];
      #pragma unroll 16
      for (int m = 0; m < 64; ++m) s += wr[160 + m] * b3[m];
      val = s * (t == 1 ? 2.f * LOG2E : -LOG2E);
    }
    biasF[t * 560 + u] = val;                        // pad units exact 0 -> h=0
  } else {
    // Wout in 16x16x16 A-frag order: entry (t,l): row p=l&15, k=t*16+(l>>4)*4+j
    for (int idx = threadIdx.x; idx < 35 * 64; idx += 256) {
      const int t = idx >> 6, l = idx & 63;
      const int p = l & 15, g = l >> 4;
      half4v w4;
      #pragma unroll
      for (int j = 0; j < 4; ++j) {
        const int u = t * 16 + g * 4 + j;
        const float v = (p < 8 && u < 548) ? Wout[p * 548 + u] : 0.f;
        w4[j] = (_Float16)v;
      }
      WoutF[idx] = __builtin_bit_cast(uint2, w4);
    }
  }
}

// ---------------------------------------------------------------------------
// Per-wave weight-stationary ntile sweep. CNT is compile-time (8 or 9) so the
// loop fully unrolls: all loads statically indexed -> compiler software-
// pipelines tile j+1 loads over tile j compute.
// ---------------------------------------------------------------------------
template <int CNT>
__device__ __forceinline__ void wave_ntiles(
    const int n0, const char* __restrict__ wfp, const uint2* __restrict__ WoutF,
    const float* __restrict__ biasF, const int lane, const int grp,
    const half8v xf[2][3], float4v acc2[2]) {
  #pragma unroll
  for (int j = 0; j < CNT; ++j) {
    const int t = n0 + j;
    const char* base = wfp + (size_t)t * 10240;
    half8v bw[3][3];                                 // W A-fragments
    #pragma unroll
    for (int g3 = 0; g3 < 3; ++g3)
      #pragma unroll
      for (int kc = 0; kc < 3; ++kc)
        bw[g3][kc] = *(const half8v*)(base + g3 * 3328 + kc * 64);
    const uint2 a2w = WoutF[t * 64 + lane];
    float4v bi[3];                                   // bias (L2-resident)
    #pragma unroll
    for (int g3 = 0; g3 < 3; ++g3)
      bi[g3] = *(const float4v*)(biasF + g3 * 560 + t * 16 + grp * 4);
    const half4v a2 = __builtin_bit_cast(half4v, a2w);

    #pragma unroll
    for (int bt = 0; bt < 2; ++bt) {                 // 2 independent streams
      float4v acc[3];
      #pragma unroll
      for (int g3 = 0; g3 < 3; ++g3) acc[g3] = bi[g3];
      // gates^T: D[unit = grp*4+r][batch = l15]
      #pragma unroll
      for (int kc = 0; kc < 3; ++kc)
        #pragma unroll
        for (int g3 = 0; g3 < 3; ++g3)
          acc[g3] = __builtin_amdgcn_mfma_f32_16x16x32_f16(
              bw[g3][kc], xf[bt][kc], acc[g3], 0, 0, 0);

      // ---- batched activation (trans ops grouped for pipe ILP) ----
      float Ei[4], Eg[4], Eo[4];
      #pragma unroll
      for (int r = 0; r < 4; ++r) {
        Ei[r] = EXP2(acc[0][r]);                     // e^{-i}
        Eg[r] = EXP2(acc[1][r]);                     // e^{2g}
        Eo[r] = EXP2(acc[2][r]);                     // e^{-o}
      }
      float c2[4];
      #pragma unroll
      for (int r = 0; r < 4; ++r) {
        const float den = (1.f + Ei[r]) * (1.f + Eg[r]);
        const float num = __builtin_fmaf(Eg[r], 2.f * LOG2E, -2.f * LOG2E);
        c2[r] = num * RCP(den);                      // = 2*log2e * c
      }
      float Ec[4];
      #pragma unroll
      for (int r = 0; r < 4; ++r) Ec[r] = EXP2(c2[r]);
      half4v hh;
      #pragma unroll
      for (int r = 0; r < 4; ++r) {
        const float den = (1.f + Eo[r]) * (1.f + Ec[r]);
        hh[r] = (_Float16)((Ec[r] - 1.f) * RCP(den));
      }
      acc2[bt] = MFMA16(a2, hh, acc2[bt]);           // logits^T[p][b] +=
    }
  }
}

// ---------------------------------------------------------------------------
__global__ __launch_bounds__(256, 8) void fused_main(
    const float* __restrict__ wv, const float* __restrict__ wt,
    const float* __restrict__ ng, const char* __restrict__ WfB,
    const float* __restrict__ biasF, const uint2* __restrict__ WoutF,
    const float* __restrict__ bout, float* __restrict__ out) {
  __shared__ __attribute__((aligned(16))) _Float16 sX[32 * 80 + 16];  // 5152 B
  __shared__ __attribute__((aligned(16))) float4v sRed[4][2][64];     // 8192 B
  // 13.4 KB LDS -> 8 blocks/CU (grid 2048/256 = 8) -> 32 waves/CU (100% cap)

  const int tid = threadIdx.x;
  const int wvi = tid >> 6, lane = tid & 63;
  const int l15 = lane & 15, grp = lane >> 4;
  const int bb0 = blockIdx.x * 32;                   // block's first batch

  // ---- stage this block's inputs f32 -> f16 LDS: sX[blk_batch][k<80] ----
  for (int i = tid; i < 384; i += 256)               // wave: k 0..11
    sX[(i / 12) * 80 + (i % 12)] = (_Float16)wv[(size_t)bb0 * 12 + i];
  for (int i = tid; i < 384; i += 256)               // wait: k 12..23
    sX[(i / 12) * 80 + 12 + (i % 12)] = (_Float16)wt[(size_t)bb0 * 12 + i];
  for (int i = tid; i < 1536; i += 256)              // neigh: k 24..71
    sX[(i / 48) * 80 + 24 + (i % 48)] = (_Float16)ng[(size_t)bb0 * 48 + i];
  for (int i = tid; i < 256; i += 256)               // pad: k 72..79
    sX[(i >> 3) * 80 + 72 + (i & 7)] = (_Float16)0.f;
  if (tid < 16) sX[32 * 80 + tid] = (_Float16)0.f;   // zeroed tail (OOB guard)
  __syncthreads();

  // X B-fragments for both batch-tiles, held in registers (24 VGPR).
  // lane=(k_grp<<4)|batch, k = kc*32 + grp*8 + j. kc=2,grp>=2 intentionally
  // overlaps the next row (Wf k>=72 is exact zero, 0*finite=0); the last row
  // is backed by the zero tail.
  half8v xf[2][3];
  #pragma unroll
  for (int bt = 0; bt < 2; ++bt)
    #pragma unroll
    for (int kc = 0; kc < 3; ++kc)
      xf[bt][kc] = *(const half8v*)&sX[(bt * 16 + l15) * 80 + kc * 32 + grp * 8];

  float4v acc2[2] = {{0.f, 0.f, 0.f, 0.f}, {0.f, 0.f, 0.f, 0.f}};  // logits^T

  const char* wfp = WfB + (size_t)l15 * 208 + (size_t)grp * 16;

  // Weight-stationary: wave 0 owns tiles 0..7; wave w>0 owns 9w-1..9w+7.
  if (wvi == 0)
    wave_ntiles<8>(0, wfp, WoutF, biasF, lane, grp, xf, acc2);
  else
    wave_ntiles<9>(9 * wvi - 1, wfp, WoutF, biasF, lane, grp, xf, acc2);

  // ---- cross-wave reduction of partial logits ----
  #pragma unroll
  for (int bt = 0; bt < 2; ++bt) sRed[wvi][bt][lane] = acc2[bt];
  __syncthreads();

  // waves 0,1 finish batch-tiles 0,1
  if (wvi < 2 && grp < 2) {
    const float4v s0 = sRed[0][wvi][lane], s1 = sRed[1][wvi][lane];
    const float4v s2 = sRed[2][wvi][lane], s3 = sRed[3][wvi][lane];
    float4v lg;
    #pragma unroll
    for (int r = 0; r < 4; ++r) lg[r] = (s0[r] + s1[r]) + (s2[r] + s3[r]);

    // lane (grp<2, b=l15) holds logits[p = grp*4+r][bb0 + wvi*16 + b]
    const float4v bo4 = *(const float4v*)(bout + grp * 4);
    float l[4];
    #pragma unroll
    for (int r = 0; r < 4; ++r) l[r] = lg[r] + bo4[r];
    float mymax = fmaxf(fmaxf(l[0], l[1]), fmaxf(l[2], l[3]));
    const float mx = fmaxf(mymax, __shfl_xor(mymax, 16, 64));
    float e[4], s = 0.f;
    #pragma unroll
    for (int r = 0; r < 4; ++r) {
      e[r] = EXP2((l[r] - mx) * LOG2E);
      s += e[r];
    }
    s += __shfl_xor(s, 16, 64);
    const float rs = RCP(s);
    float4v res;
    #pragma unroll
    for (int r = 0; r < 4; ++r) res[r] = e[r] * rs;
    const int batch = bb0 + wvi * 16 + l15;
    *(float4v*)(out + (size_t)batch * 8 + grp * 4) = res;
  }
}

// ---------------------------------------------------------------------------
extern "C" void kernel_launch(void* const* d_in, const int* in_sizes, int n_in,
                              void* d_out, int out_size, void* d_ws, size_t ws_size,
                              hipStream_t stream) {
  const float* wave  = (const float*)d_in[0];
  const float* wait_ = (const float*)d_in[1];
  const float* neigh = (const float*)d_in[2];
  const float* W1    = (const float*)d_in[3];
  const float* b1    = (const float*)d_in[4];
  const float* W2    = (const float*)d_in[5];
  const float* b2    = (const float*)d_in[6];
  const float* W3    = (const float*)d_in[7];
  const float* b3    = (const float*)d_in[8];
  const float* Wih   = (const float*)d_in[9];
  // d_in[10] = Whh  (unused: h0 == 0)
  const float* bih   = (const float*)d_in[11];
  const float* bhh   = (const float*)d_in[12];
  const float* Wout  = (const float*)d_in[13];
  const float* bout  = (const float*)d_in[14];
  // d_in[15] = h0, d_in[16] = c0 (zero, unused)
  float* out = (float*)d_out;

  char* ws = (char*)d_ws;
  unsigned short* Wf = (unsigned short*)(ws);        //      0 .. 358400
  float* biasF = (float*)(ws + 358400);              // 358400 .. 365120
  uint2* WoutF = (uint2*)(ws + 365120);              // 365120 .. 383040 (383 KB total)

  hipLaunchKernelGGL(prep_wb, dim3(638), dim3(256), 0, stream,
                     Wih, W1, W2, W3, b1, b2, b3, bih, bhh, Wout, Wf, biasF, WoutF);
  hipLaunchKernelGGL(fused_main, dim3(2048), dim3(256), 0, stream,
                     wave, wait_, neigh, (const char*)Wf, biasF, WoutF, bout, out);
}